// Round 1
// baseline (180.412 us; speedup 1.0000x reference)
//
#include <hip/hip_runtime.h>
#include <hip/hip_fp16.h>

// GAT: N=4096 nodes, F=512 in-feats, H=8 heads, D=64 head-dim.
// out[n, h*64+d] = relu( softmax_j(leaky(e_s[h,i]+e_n[h,j]) + mask) @ feats[h] + b )
//
// Pipeline:
//  prep:  cast X->f16, transpose W -> WT[h][d][f] f16
//  feats: featsT[h][d][n] = (W^T X^T) via mfma_f32_16x16x32_f16; also e_self/e_neigh (fp32)
//  attn:  flash-style over j-tiles of 64; block = 16 query rows x ALL 8 heads
//         (A tile read once from HBM per block, shared by heads via LDS)

#define NODES 4096
#define FEAT  512
#define HEADS 8
#define DH    64

using half8 = __attribute__((ext_vector_type(8))) _Float16;
using f32x4 = __attribute__((ext_vector_type(4))) float;
using f32x2 = __attribute__((ext_vector_type(2))) float;

// ---------------- prep: cast X to f16, W[h][f][d] -> WT[h][d][f] f16 ----------------
__global__ void prep_kernel(const float* __restrict__ X, const float* __restrict__ W,
                            _Float16* __restrict__ Xh, _Float16* __restrict__ WT) {
    int idx = blockIdx.x * blockDim.x + threadIdx.x;
    const int nx = NODES * FEAT;
    if (idx < nx) {
        Xh[idx] = (_Float16)X[idx];
    } else {
        int t = idx - nx;  // enumerates WT output index: h*D*F + d*F + f
        if (t < HEADS * DH * FEAT) {
            int h   = t / (DH * FEAT);
            int rem = t - h * (DH * FEAT);
            int d   = rem / FEAT;
            int f   = rem - d * FEAT;
            WT[t] = (_Float16)W[(h * FEAT + f) * DH + d];
        }
    }
}

// ---------------- feats: featsT[h][d][n] = sum_f WT[h][d][f] * X[n][f] ----------------
// grid (N/64, H), block 256 (4 waves). Wave w computes d=0..63 x n-tile of 16.
// MFMA 16x16x32_f16: A=WT (M=d,K=f), B=X^T (K=f,N=n). Both fragments are
// contiguous 16B loads from row-major storage.
__global__ __launch_bounds__(256) void feats_kernel(
    const _Float16* __restrict__ Xh, const _Float16* __restrict__ WT,
    const float* __restrict__ a_self, const float* __restrict__ a_neigh,
    _Float16* __restrict__ featsT, float* __restrict__ e_self, float* __restrict__ e_neigh) {
    const int h    = blockIdx.y;
    const int tid  = threadIdx.x;
    const int w    = tid >> 6;
    const int lane = tid & 63;
    const int l15  = lane & 15;
    const int g    = lane >> 4;
    const int n0   = blockIdx.x * 64 + w * 16;

    f32x4 acc[4] = {};
    const _Float16* xb = Xh + (n0 + l15) * FEAT + g * 8;        // B: col n = l15, k = 32kk+8g+e
    const _Float16* wb = WT + (h * DH + l15) * FEAT + g * 8;    // A: row d = 16mi+l15, same k

#pragma unroll
    for (int kk = 0; kk < FEAT / 32; ++kk) {
        half8 b = *(const half8*)(xb + kk * 32);
#pragma unroll
        for (int mi = 0; mi < 4; ++mi) {
            half8 a = *(const half8*)(wb + mi * 16 * FEAT + kk * 32);
            acc[mi] = __builtin_amdgcn_mfma_f32_16x16x32_f16(a, b, acc[mi], 0, 0, 0);
        }
    }

    // Epilogue: D-frag row = d = 16*mi + 4*g + r, col = n = n0 + l15.
    float ps = 0.f, pn = 0.f;
#pragma unroll
    for (int mi = 0; mi < 4; ++mi) {
#pragma unroll
        for (int r = 0; r < 4; ++r) {
            int d = mi * 16 + g * 4 + r;
            float v = acc[mi][r];
            featsT[(h * DH + d) * NODES + n0 + l15] = (_Float16)v;
            ps += v * a_self[h * DH + d];
            pn += v * a_neigh[h * DH + d];
        }
    }
    // column sums over d: reduce across the 4 lane-groups (same l15)
    ps += __shfl_xor(ps, 16); ps += __shfl_xor(ps, 32);
    pn += __shfl_xor(pn, 16); pn += __shfl_xor(pn, 32);
    if (g == 0) {
        e_self[h * NODES + n0 + l15]  = ps;
        e_neigh[h * NODES + n0 + l15] = pn;
    }
}

// ---------------- attn: flash over j; block = 16 rows x 8 heads ----------------
// grid N/16 = 256 blocks, block 512 threads = 8 waves, wave h handles head h.
// Per j-tile (64 cols): stage A[16][64] fp32 in LDS (double-buffered, padded to 68
// words so ds_read_b128 across 16 rows spreads banks).
__global__ __launch_bounds__(512) void attn_kernel(
    const float* __restrict__ A, const _Float16* __restrict__ featsT,
    const float* __restrict__ e_self, const float* __restrict__ e_neigh,
    const float* __restrict__ bias, float* __restrict__ out) {
    __shared__ float As[2][16][68];

    const int tid  = threadIdx.x;
    const int h    = tid >> 6;      // wave id = head
    const int lane = tid & 63;
    const int l15  = lane & 15;
    const int g    = lane >> 4;
    const int i0   = blockIdx.x * 16;

    // cooperative A staging: thread covers 2 consecutive floats
    const int srow = tid >> 5;           // 0..15
    const int scol = (tid & 31) * 2;     // 0..62
    const float* aptr = A + (size_t)(i0 + srow) * NODES + scol;

    f32x2 pre = *(const f32x2*)(aptr);   // prefetch tile 0

    const float es = e_self[h * NODES + i0 + l15];
    const float* enb = e_neigh + h * NODES;
    const _Float16* vbase = featsT + (size_t)(h * DH) * NODES;

    float m = -INFINITY, lsum = 0.f;
    f32x4 acc[4] = {};

    for (int jt = 0; jt < NODES / 64; ++jt) {
        const int cur = jt & 1;
        *(f32x2*)(&As[cur][srow][scol]) = pre;
        if (jt + 1 < NODES / 64) pre = *(const f32x2*)(aptr + (size_t)(jt + 1) * 64);
        __syncthreads();  // single barrier/iter: double buffer makes it safe

        const int j0 = jt * 64;

        // S in MFMA-A layout: lane holds rows l15, cols k = 32kk + 8g + (0..7)
        float s[16];
#pragma unroll
        for (int kk = 0; kk < 2; ++kk) {
#pragma unroll
            for (int q = 0; q < 2; ++q) {
                f32x4 en = *(const f32x4*)(enb + j0 + kk * 32 + g * 8 + q * 4);
                f32x4 av = *(const f32x4*)(&As[cur][l15][kk * 32 + g * 8 + q * 4]);
#pragma unroll
                for (int e = 0; e < 4; ++e) {
                    float x = es + en[e];
                    x = fmaxf(x, 0.2f * x);            // LeakyReLU(0.2), exact
                    x += av[e] * 1e10f - 1e10f;        // + NEG_INF*(1-A)
                    s[kk * 8 + q * 4 + e] = x;
                }
            }
        }

        // online softmax: row reduce (16 local + lanes ^16 ^32 share same row l15)
        float tmax = s[0];
#pragma unroll
        for (int i = 1; i < 16; ++i) tmax = fmaxf(tmax, s[i]);
        tmax = fmaxf(tmax, __shfl_xor(tmax, 16));
        tmax = fmaxf(tmax, __shfl_xor(tmax, 32));
        float mnew  = fmaxf(m, tmax);
        float scale = __expf(m - mnew);
        m = mnew;

        float psum = 0.f;
#pragma unroll
        for (int i = 0; i < 16; ++i) {
            float p = __expf(s[i] - mnew);
            s[i] = p;
            psum += p;
        }
        psum += __shfl_xor(psum, 16);
        psum += __shfl_xor(psum, 32);
        lsum = lsum * scale + psum;

        // rescale acc: acc rows are 4g+r (D-layout); scale lives at lane (row&15)
        float sr[4];
#pragma unroll
        for (int r = 0; r < 4; ++r) sr[r] = __shfl(scale, g * 4 + r);
#pragma unroll
        for (int ni = 0; ni < 4; ++ni)
#pragma unroll
            for (int r = 0; r < 4; ++r) acc[ni][r] *= sr[r];

        // P -> f16 A-frags (already in the right per-lane layout)
        half8 pa[2];
#pragma unroll
        for (int kk = 0; kk < 2; ++kk)
#pragma unroll
            for (int e = 0; e < 8; ++e) pa[kk][e] = (_Float16)s[kk * 8 + e];

        // V B-frags: featsT[h][d = 16ni+l15][j0 + 32kk + 8g + 0..7] contiguous 16B
#pragma unroll
        for (int ni = 0; ni < 4; ++ni) {
            const _Float16* vp = vbase + (size_t)(ni * 16 + l15) * NODES + j0 + g * 8;
#pragma unroll
            for (int kk = 0; kk < 2; ++kk) {
                half8 vb = *(const half8*)(vp + kk * 32);
                acc[ni] = __builtin_amdgcn_mfma_f32_16x16x32_f16(pa[kk], vb, acc[ni], 0, 0, 0);
            }
        }
    }

    // epilogue: out[i0+4g+r][h*64 + 16ni + l15] = relu(acc/lsum + b)
    float inv = 1.0f / lsum;
    float invr[4];
#pragma unroll
    for (int r = 0; r < 4; ++r) invr[r] = __shfl(inv, g * 4 + r);
#pragma unroll
    for (int ni = 0; ni < 4; ++ni) {
        int d = ni * 16 + l15;
        float bb = bias[h * DH + d];
#pragma unroll
        for (int r = 0; r < 4; ++r) {
            float v = acc[ni][r] * invr[r] + bb;
            v = fmaxf(v, 0.f);
            out[(size_t)(i0 + g * 4 + r) * (HEADS * DH) + h * DH + d] = v;
        }
    }
}

extern "C" void kernel_launch(void* const* d_in, const int* in_sizes, int n_in,
                              void* d_out, int out_size, void* d_ws, size_t ws_size,
                              hipStream_t stream) {
    const float* X       = (const float*)d_in[0];
    const float* A       = (const float*)d_in[1];
    const float* W       = (const float*)d_in[2];
    const float* b       = (const float*)d_in[3];
    const float* a_self  = (const float*)d_in[4];
    const float* a_neigh = (const float*)d_in[5];
    float* out = (float*)d_out;

    char* ws = (char*)d_ws;
    _Float16* Xh     = (_Float16*)ws;                                  // 4 MB
    _Float16* WT     = (_Float16*)(ws + 4u * 1024 * 1024);             // 512 KB
    _Float16* featsT = (_Float16*)(ws + 4u * 1024 * 1024 + 512 * 1024);// 4 MB
    float* e_self    = (float*)(ws + 8u * 1024 * 1024 + 512 * 1024);   // 128 KB
    float* e_neigh   = e_self + HEADS * NODES;                         // 128 KB

    const int total = NODES * FEAT + HEADS * DH * FEAT;
    prep_kernel<<<(total + 255) / 256, 256, 0, stream>>>(X, W, Xh, WT);
    feats_kernel<<<dim3(NODES / 64, HEADS), 256, 0, stream>>>(
        Xh, WT, a_self, a_neigh, featsT, e_self, e_neigh);
    attn_kernel<<<NODES / 16, 512, 0, stream>>>(A, featsT, e_self, e_neigh, b, out);
}